// Round 5
// baseline (252.599 us; speedup 1.0000x reference)
//
#include <hip/hip_runtime.h>
#include <hip/hip_bf16.h>

// Problem constants
#define BB 8
#define TT 2048
#define EE 1024
#define HH 64

typedef __attribute__((ext_vector_type(8))) short short8;
typedef __attribute__((ext_vector_type(4))) float f32x4;

__device__ inline f32x4 mfma_16x16x32(short8 a, short8 b, f32x4 c) {
  return __builtin_amdgcn_mfma_f32_16x16x32_bf16(a, b, c, 0, 0, 0);
}

// async global->LDS, 16B per lane, LDS dest = wave-uniform base + lane*16
__device__ inline void gload_lds16(const __hip_bfloat16* g, __hip_bfloat16* l) {
  __builtin_amdgcn_global_load_lds((const __attribute__((address_space(1))) void*)g,
                                   (__attribute__((address_space(3))) void*)l,
                                   16, 0, 0);
}

__device__ inline short f2bf(float f) {
  __hip_bfloat16 h = __float2bfloat16(f);
  return *reinterpret_cast<short*>(&h);
}
__device__ inline float bf2f(short s) {
  __hip_bfloat16 h = *reinterpret_cast<__hip_bfloat16*>(&s);
  return __bfloat162float(h);
}

// wait lgkmcnt(0) only; leave vmcnt/expcnt unconstrained (vmcnt=63, expcnt=7)
#define WAIT_LGKM0() __builtin_amdgcn_s_waitcnt(0xC07F)

// ---------------------------------------------------------------------------
// Kernel 0: split-precision transposed weights (unchanged).
// ---------------------------------------------------------------------------
__global__ void prep_w(const float* __restrict__ Wq, const float* __restrict__ Wk,
                       const float* __restrict__ Wv,
                       __hip_bfloat16* __restrict__ Wthi,
                       __hip_bfloat16* __restrict__ Wtlo) {
  const int n = blockIdx.x;          // 0..191
  const int m = n >> 6;
  const int h = n & 63;
  const float* W = (m == 0) ? Wq : (m == 1) ? Wk : Wv;
  const int e0 = threadIdx.x * 4;    // 256 threads * 4 = 1024
#pragma unroll
  for (int j = 0; j < 4; ++j) {
    const float w = W[(e0 + j) * 64 + h];
    const __hip_bfloat16 hi = __float2bfloat16(w);
    Wthi[n * 1024 + e0 + j] = hi;
    Wtlo[n * 1024 + e0 + j] = __float2bfloat16(w - __bfloat162float(hi));
  }
}

// ---------------------------------------------------------------------------
// Kernel A (unchanged this round): split-bf16 fp32-emulated GEMM.
// ---------------------------------------------------------------------------
__global__ __launch_bounds__(256) void qkv_gemm(
    const float* __restrict__ x,
    const __hip_bfloat16* __restrict__ Wthi, const __hip_bfloat16* __restrict__ Wtlo,
    __hip_bfloat16* __restrict__ qhi, __hip_bfloat16* __restrict__ qlo,
    __hip_bfloat16* __restrict__ khi, __hip_bfloat16* __restrict__ klo,
    __hip_bfloat16* __restrict__ vT) {
  __shared__ __hip_bfloat16 Ahi[2][64 * 72];
  __shared__ __hip_bfloat16 Alo[2][64 * 72];
  __shared__ __hip_bfloat16 Bhi[2][192 * 64];
  __shared__ __hip_bfloat16 Blo[2][128 * 64];

  const int tid  = threadIdx.x;
  const int wave = tid >> 6;
  const int lane = tid & 63;
  const int row0 = blockIdx.x * 64;

  const int lr = tid >> 2;
  const int le = (tid & 3) * 16;
  const float* xrow = x + (row0 + lr) * 1024 + le;

  f32x4 acc[12];
#pragma unroll
  for (int j = 0; j < 12; ++j) acc[j] = f32x4{0.f, 0.f, 0.f, 0.f};

  const int l15 = lane & 15, l4 = lane >> 4;

  auto issue_B = [&](int c, int buf) {
    const int g = (lane & 7) ^ ((lane >> 3) & 7);
#pragma unroll
    for (int s = 0; s < 6; ++s) {
      const int qq = wave * 6 + s;
      const int n  = qq * 8 + (lane >> 3);
      gload_lds16(Wthi + n * 1024 + c * 64 + g * 8, &Bhi[buf][qq * 512]);
      if (qq < 16)
        gload_lds16(Wtlo + n * 1024 + c * 64 + g * 8, &Blo[buf][qq * 512]);
    }
  };
  auto write_A = [&](int buf, const f32x4* xr) {
    short8 h0, h1, l0, l1;
    const float* xf = (const float*)xr;
#pragma unroll
    for (int j = 0; j < 8; ++j) {
      const float v = xf[j];
      const short h = f2bf(v);
      h0[j] = h;
      l0[j] = f2bf(v - bf2f(h));
    }
#pragma unroll
    for (int j = 0; j < 8; ++j) {
      const float v = xf[8 + j];
      const short h = f2bf(v);
      h1[j] = h;
      l1[j] = f2bf(v - bf2f(h));
    }
    *(short8*)&Ahi[buf][lr * 72 + le]     = h0;
    *(short8*)&Ahi[buf][lr * 72 + le + 8] = h1;
    *(short8*)&Alo[buf][lr * 72 + le]     = l0;
    *(short8*)&Alo[buf][lr * 72 + le + 8] = l1;
  };
  auto compute = [&](int buf) {
    const int tr = wave * 16 + l15;
    short8 ah0 = *(const short8*)&Ahi[buf][tr * 72 + l4 * 8];
    short8 ah1 = *(const short8*)&Ahi[buf][tr * 72 + 32 + l4 * 8];
    short8 al0 = *(const short8*)&Alo[buf][tr * 72 + l4 * 8];
    short8 al1 = *(const short8*)&Alo[buf][tr * 72 + 32 + l4 * 8];
#pragma unroll
    for (int j = 0; j < 12; ++j) {
      const int n  = j * 16 + l15;
      const int o0 = ((l4)     ^ (n & 7)) * 8;
      const int o1 = ((4 + l4) ^ (n & 7)) * 8;
      short8 bh0 = *(const short8*)&Bhi[buf][n * 64 + o0];
      short8 bh1 = *(const short8*)&Bhi[buf][n * 64 + o1];
      acc[j] = mfma_16x16x32(ah0, bh0, acc[j]);
      acc[j] = mfma_16x16x32(ah1, bh1, acc[j]);
      if (j < 8) {
        short8 bl0 = *(const short8*)&Blo[buf][n * 64 + o0];
        short8 bl1 = *(const short8*)&Blo[buf][n * 64 + o1];
        acc[j] = mfma_16x16x32(ah0, bl0, acc[j]);
        acc[j] = mfma_16x16x32(ah1, bl1, acc[j]);
        acc[j] = mfma_16x16x32(al0, bh0, acc[j]);
        acc[j] = mfma_16x16x32(al1, bh1, acc[j]);
      }
    }
  };

  f32x4 xr[4], xn[4];
  {
    const f32x4* p = (const f32x4*)xrow;
    xr[0] = p[0]; xr[1] = p[1]; xr[2] = p[2]; xr[3] = p[3];
  }
  issue_B(0, 0);
  __builtin_amdgcn_s_waitcnt(0);
  write_A(0, xr);
  __syncthreads();

  for (int c = 0; c < 16; ++c) {
    const int p = c & 1;
    if (c < 15) {
      const f32x4* pp = (const f32x4*)(xrow + (c + 1) * 64);
      xn[0] = pp[0]; xn[1] = pp[1]; xn[2] = pp[2]; xn[3] = pp[3];
      issue_B(c + 1, p ^ 1);
    }
    compute(p);
    if (c < 15) {
      __builtin_amdgcn_s_waitcnt(0);
      write_A(p ^ 1, xn);
    }
    __syncthreads();
  }

  const int strip = wave * 16;
#pragma unroll
  for (int j = 0; j < 12; ++j) {
    const int n  = j * 16 + l15;
    const int mm = n >> 6;
    const int h  = n & 63;
#pragma unroll
    for (int r = 0; r < 4; ++r) {
      const int trow = row0 + strip + l4 * 4 + r;
      const float val = acc[j][r];
      const __hip_bfloat16 hi = __float2bfloat16(val);
      const __hip_bfloat16 lo = __float2bfloat16(val - __bfloat162float(hi));
      if (mm == 0) {
        qhi[trow * 64 + h] = hi;
        qlo[trow * 64 + h] = lo;
      } else if (mm == 1) {
        khi[trow * 64 + h] = hi;
        klo[trow * 64 + h] = lo;
      } else {
        const int bb = trow >> 11, tl = trow & 2047;
        vT[(bb * 64 + h) * 2048 + tl] = hi;
      }
    }
  }
}

// ---------------------------------------------------------------------------
// Kernel B v4: FLAT balanced split-K flash attention.
// Wave-unit = (b, 64-row strip s, chunk ci of min(8,s+1) near-equal chunks of
// the s+1 causal K-tiles). 228 units/batch, 1824 waves = 456 blocks x 4 waves,
// reversed so 4-tile units start first. Each wave writes normalized bf16
// partial O (row-major) + fp32 (m,l) to workspace; attn_merge combines.
// LDS = Psm only (37 KB) -> 2 blocks/CU co-resident.
// ---------------------------------------------------------------------------
__global__ __launch_bounds__(256, 2) void attn_part(
    const __hip_bfloat16* __restrict__ qhi, const __hip_bfloat16* __restrict__ qlo,
    const __hip_bfloat16* __restrict__ khi, const __hip_bfloat16* __restrict__ klo,
    const __hip_bfloat16* __restrict__ vT,
    __hip_bfloat16* __restrict__ partO, float* __restrict__ partM,
    float* __restrict__ partL) {
  __shared__ __hip_bfloat16 Psm[4][64 * 72];   // per-wave P, padded

  const int tid  = threadIdx.x;
  const int wave = tid >> 6;
  const int lane = tid & 63;
  const int l15 = lane & 15, l4 = lane >> 4;

  // ---- decode flat wave unit (reversed: big chunks first) ----
  const int w = 1823 - (blockIdx.x * 4 + wave);   // 0..1823
  const int b = w / 228;
  int v = w % 228;
  int s, ci;
  if (v < 28) {            // strips 0..6: s+1 single-tile chunks
    s = 0;
    while (v >= s + 1) { v -= s + 1; ++s; }
    ci = v;
  } else {                 // strips 7..31: 8 chunks each
    const int g = v - 28;
    s = 7 + (g >> 3);
    ci = g & 7;
  }
  const int ntile = s + 1;
  const int nch   = (ntile < 8) ? ntile : 8;
  const int base  = ntile / nch, rem = ntile % nch;
  const int tb    = ci * base + ((ci < rem) ? ci : rem);
  const int tcnt  = base + ((ci < rem) ? 1 : 0);
  const int t0    = s * 64;
  const int pidx  = (b * 32 + s) * 8 + ci;

  // ---- Q A-frags for 4 sub-tiles, hi+lo, in regs throughout ----
  short8 qh0[4], qh1[4], ql0[4], ql1[4];
#pragma unroll
  for (int m = 0; m < 4; ++m) {
    const __hip_bfloat16* qph = qhi + (b * 2048 + t0 + m * 16 + l15) * 64;
    const __hip_bfloat16* qpl = qlo + (b * 2048 + t0 + m * 16 + l15) * 64;
    qh0[m] = *(const short8*)(qph + l4 * 8);
    qh1[m] = *(const short8*)(qph + 32 + l4 * 8);
    ql0[m] = *(const short8*)(qpl + l4 * 8);
    ql1[m] = *(const short8*)(qpl + 32 + l4 * 8);
  }

  f32x4 acc[4][4];
#pragma unroll
  for (int m = 0; m < 4; ++m)
#pragma unroll
    for (int j = 0; j < 4; ++j) acc[m][j] = f32x4{0.f, 0.f, 0.f, 0.f};
  float m_[4][4], l_[4][4];
#pragma unroll
  for (int m = 0; m < 4; ++m)
#pragma unroll
    for (int r = 0; r < 4; ++r) { m_[m][r] = -1e30f; l_[m][r] = 0.f; }

  const __hip_bfloat16* kbase_h = khi + (size_t)b * 2048 * 64;
  const __hip_bfloat16* kbase_l = klo + (size_t)b * 2048 * 64;
  const __hip_bfloat16* vbase   = vT + (size_t)b * 64 * 2048;

  for (int tt = 0; tt < tcnt; ++tt) {
    const int kt = tb + tt;
    const int k0 = kt << 6;
    const bool diag = (kt == s);

    // ---- K frags (shared across the 4 Q sub-tiles) ----
    short8 kh0[4], kh1[4], kl0[4], kl1[4];
#pragma unroll
    for (int j = 0; j < 4; ++j) {
      const __hip_bfloat16* kph = kbase_h + (k0 + j * 16 + l15) * 64;
      const __hip_bfloat16* kpl = kbase_l + (k0 + j * 16 + l15) * 64;
      kh0[j] = *(const short8*)(kph + l4 * 8);
      kh1[j] = *(const short8*)(kph + 32 + l4 * 8);
      kl0[j] = *(const short8*)(kpl + l4 * 8);
      kl1[j] = *(const short8*)(kpl + 32 + l4 * 8);
    }

    // ---- per sub-tile: S, mask, online softmax, P->LDS ----
#pragma unroll
    for (int m = 0; m < 4; ++m) {
      f32x4 s_[4];
#pragma unroll
      for (int j = 0; j < 4; ++j) {
        if (diag && j > m) {
          s_[j] = f32x4{-1e30f, -1e30f, -1e30f, -1e30f};
          continue;
        }
        f32x4 z = f32x4{0.f, 0.f, 0.f, 0.f};
        z = mfma_16x16x32(qh0[m], kh0[j], z);
        z = mfma_16x16x32(qh1[m], kh1[j], z);
        z = mfma_16x16x32(qh0[m], kl0[j], z);
        z = mfma_16x16x32(qh1[m], kl1[j], z);
        z = mfma_16x16x32(ql0[m], kh0[j], z);
        z = mfma_16x16x32(ql1[m], kh1[j], z);
        s_[j] = z;
      }
      if (diag) {   // partial mask on the j == m sub-block
        const int key = m * 16 + l15;
#pragma unroll
        for (int r = 0; r < 4; ++r) {
          const int row = m * 16 + l4 * 4 + r;
          if (key > row) s_[m][r] = -1e30f;
        }
      }

      float mx[4], rs[4], al[4];
#pragma unroll
      for (int r = 0; r < 4; ++r)
        mx[r] = fmaxf(fmaxf(s_[0][r], s_[1][r]), fmaxf(s_[2][r], s_[3][r]));
      for (int off = 1; off < 16; off <<= 1) {
#pragma unroll
        for (int r = 0; r < 4; ++r) mx[r] = fmaxf(mx[r], __shfl_xor(mx[r], off));
      }
#pragma unroll
      for (int r = 0; r < 4; ++r) {
        const float mn = fmaxf(m_[m][r], mx[r]);
        al[r] = __expf(m_[m][r] - mn);
        m_[m][r] = mn;
        rs[r] = 0.f;
      }
#pragma unroll
      for (int j = 0; j < 4; ++j) {
#pragma unroll
        for (int r = 0; r < 4; ++r) {
          const float pv = __expf(s_[j][r] - m_[m][r]);
          s_[j][r] = pv;
          rs[r] += pv;
        }
      }
      for (int off = 1; off < 16; off <<= 1) {
#pragma unroll
        for (int r = 0; r < 4; ++r) rs[r] += __shfl_xor(rs[r], off);
      }
#pragma unroll
      for (int r = 0; r < 4; ++r) l_[m][r] = l_[m][r] * al[r] + rs[r];
#pragma unroll
      for (int j = 0; j < 4; ++j)
#pragma unroll
        for (int r = 0; r < 4; ++r) acc[m][j][r] *= al[r];

#pragma unroll
      for (int j = 0; j < 4; ++j)
#pragma unroll
        for (int r = 0; r < 4; ++r)
          Psm[wave][(m * 16 + l4 * 4 + r) * 72 + j * 16 + l15] =
              __float2bfloat16(s_[j][r]);
    }

    // ---- V frags (stay in flight across the lgkm-only wait) ----
    short8 vf0[4], vf1[4];
#pragma unroll
    for (int j = 0; j < 4; ++j) {
      const __hip_bfloat16* vp = vbase + (j * 16 + l15) * 2048 + k0;
      vf0[j] = *(const short8*)(vp + l4 * 8);
      vf1[j] = *(const short8*)(vp + 32 + l4 * 8);
    }

    WAIT_LGKM0();   // P LDS write->read only; vmcnt untouched

    // ---- O += P V ----
#pragma unroll
    for (int m = 0; m < 4; ++m) {
      short8 pf0 = *(const short8*)&Psm[wave][(m * 16 + l15) * 72 + l4 * 8];
      short8 pf1 = *(const short8*)&Psm[wave][(m * 16 + l15) * 72 + 32 + l4 * 8];
#pragma unroll
      for (int j = 0; j < 4; ++j) {
        acc[m][j] = mfma_16x16x32(pf0, vf0[j], acc[m][j]);
        acc[m][j] = mfma_16x16x32(pf1, vf1[j], acc[m][j]);
      }
    }
  }

  // ---- epilogue: normalized bf16 partial O + fp32 (m,l) ----
#pragma unroll
  for (int m = 0; m < 4; ++m) {
    float inv[4];
#pragma unroll
    for (int r = 0; r < 4; ++r) inv[r] = (l_[m][r] > 0.f) ? 1.f / l_[m][r] : 0.f;
#pragma unroll
    for (int j = 0; j < 4; ++j)
#pragma unroll
      for (int r = 0; r < 4; ++r)
        partO[(size_t)pidx * 4096 + (m * 16 + l4 * 4 + r) * 64 + j * 16 + l15] =
            __float2bfloat16(acc[m][j][r] * inv[r]);
    if (l15 == 0) {
#pragma unroll
      for (int r = 0; r < 4; ++r) {
        partM[pidx * 64 + m * 16 + l4 * 4 + r] = m_[m][r];
        partL[pidx * 64 + m * 16 + l4 * 4 + r] = l_[m][r];
      }
    }
  }
}

// ---------------------------------------------------------------------------
// Kernel C: merge <=8 partials per (b, strip). Grid 256 blocks x 256 threads.
// O_full = sum_c a_c*l_c*Ohat_c / sum_c a_c*l_c, a_c = exp(m_c - M).
// ---------------------------------------------------------------------------
__global__ __launch_bounds__(256) void attn_merge(
    const __hip_bfloat16* __restrict__ partO, const float* __restrict__ partM,
    const float* __restrict__ partL, float* __restrict__ out) {
  const int bs = blockIdx.x;          // b*32 + s
  const int b = bs >> 5, s = bs & 31;
  const int nch = (s + 1 < 8) ? (s + 1) : 8;
  const int tid = threadIdx.x;
  const int h = tid & 63, rg = tid >> 6;

#pragma unroll 4
  for (int rr = 0; rr < 16; ++rr) {
    const int row = rg * 16 + rr;
    float M = -1e30f;
    for (int c = 0; c < nch; ++c)
      M = fmaxf(M, partM[(bs * 8 + c) * 64 + row]);
    float L = 0.f, O = 0.f;
    for (int c = 0; c < nch; ++c) {
      const float a = __expf(partM[(bs * 8 + c) * 64 + row] - M) *
                      partL[(bs * 8 + c) * 64 + row];
      L += a;
      O += a * __bfloat162float(
               partO[(size_t)(bs * 8 + c) * 4096 + row * 64 + h]);
    }
    out[(b * 2048 + s * 64 + row) * 64 + h] = O / L;
  }
}

// ---------------------------------------------------------------------------
extern "C" void kernel_launch(void* const* d_in, const int* in_sizes, int n_in,
                              void* d_out, int out_size, void* d_ws, size_t ws_size,
                              hipStream_t stream) {
  const float* x  = (const float*)d_in[0];
  const float* Wq = (const float*)d_in[1];
  const float* Wk = (const float*)d_in[2];
  const float* Wv = (const float*)d_in[3];
  float* out = (float*)d_out;

  char* ws = (char*)d_ws;
  __hip_bfloat16* Wthi = (__hip_bfloat16*)ws;                   // 384 KB
  __hip_bfloat16* Wtlo = (__hip_bfloat16*)(ws + 393216);        // 384 KB
  __hip_bfloat16* qhi  = (__hip_bfloat16*)(ws + 786432);        // 2 MB each
  __hip_bfloat16* qlo  = (__hip_bfloat16*)(ws + 786432 + 1 * 2097152);
  __hip_bfloat16* khi  = (__hip_bfloat16*)(ws + 786432 + 2 * 2097152);
  __hip_bfloat16* klo  = (__hip_bfloat16*)(ws + 786432 + 3 * 2097152);
  __hip_bfloat16* vT   = (__hip_bfloat16*)(ws + 786432 + 4 * 2097152);
  char* p = ws + 786432 + 5 * 2097152;                          // 11.27 MB
  __hip_bfloat16* partO = (__hip_bfloat16*)p;                   // 16.78 MB
  float* partM = (float*)(p + 16777216);                        // 512 KB
  float* partL = (float*)(p + 16777216 + 524288);               // 512 KB

  prep_w<<<192, 256, 0, stream>>>(Wq, Wk, Wv, Wthi, Wtlo);
  qkv_gemm<<<256, 256, 0, stream>>>(x, Wthi, Wtlo, qhi, qlo, khi, klo, vT);
  attn_part<<<456, 256, 0, stream>>>(qhi, qlo, khi, klo, vT, partO, partM, partL);
  attn_merge<<<256, 256, 0, stream>>>(partO, partM, partL, out);
}

// Round 6
// 242.370 us; speedup vs baseline: 1.0422x; 1.0422x over previous
//
#include <hip/hip_runtime.h>
#include <hip/hip_bf16.h>

// Problem constants
#define BB 8
#define TT 2048
#define EE 1024
#define HH 64

typedef __attribute__((ext_vector_type(8))) short short8;
typedef __attribute__((ext_vector_type(4))) float f32x4;

__device__ inline f32x4 mfma_16x16x32(short8 a, short8 b, f32x4 c) {
  return __builtin_amdgcn_mfma_f32_16x16x32_bf16(a, b, c, 0, 0, 0);
}

// async global->LDS, 16B per lane, LDS dest = wave-uniform base + lane*16
__device__ inline void gload_lds16(const __hip_bfloat16* g, __hip_bfloat16* l) {
  __builtin_amdgcn_global_load_lds((const __attribute__((address_space(1))) void*)g,
                                   (__attribute__((address_space(3))) void*)l,
                                   16, 0, 0);
}

__device__ inline short f2bf(float f) {
  __hip_bfloat16 h = __float2bfloat16(f);
  return *reinterpret_cast<short*>(&h);
}
__device__ inline float bf2f(short s) {
  __hip_bfloat16 h = *reinterpret_cast<__hip_bfloat16*>(&s);
  return __bfloat162float(h);
}

// wait lgkmcnt(0) only; leave vmcnt/expcnt unconstrained
#define WAIT_LGKM0() __builtin_amdgcn_s_waitcnt(0xC07F)

// ---------------------------------------------------------------------------
// Kernel 0: split-precision transposed weights (unchanged).
// ---------------------------------------------------------------------------
__global__ void prep_w(const float* __restrict__ Wq, const float* __restrict__ Wk,
                       const float* __restrict__ Wv,
                       __hip_bfloat16* __restrict__ Wthi,
                       __hip_bfloat16* __restrict__ Wtlo) {
  const int n = blockIdx.x;          // 0..191
  const int m = n >> 6;
  const int h = n & 63;
  const float* W = (m == 0) ? Wq : (m == 1) ? Wk : Wv;
  const int e0 = threadIdx.x * 4;    // 256 threads * 4 = 1024
#pragma unroll
  for (int j = 0; j < 4; ++j) {
    const float w = W[(e0 + j) * 64 + h];
    const __hip_bfloat16 hi = __float2bfloat16(w);
    Wthi[n * 1024 + e0 + j] = hi;
    Wtlo[n * 1024 + e0 + j] = __float2bfloat16(w - __bfloat162float(hi));
  }
}

// ---------------------------------------------------------------------------
// Kernel A (unchanged this round): split-bf16 fp32-emulated GEMM.
// ---------------------------------------------------------------------------
__global__ __launch_bounds__(256) void qkv_gemm(
    const float* __restrict__ x,
    const __hip_bfloat16* __restrict__ Wthi, const __hip_bfloat16* __restrict__ Wtlo,
    __hip_bfloat16* __restrict__ qhi, __hip_bfloat16* __restrict__ qlo,
    __hip_bfloat16* __restrict__ khi, __hip_bfloat16* __restrict__ klo,
    __hip_bfloat16* __restrict__ vT) {
  __shared__ __hip_bfloat16 Ahi[2][64 * 72];
  __shared__ __hip_bfloat16 Alo[2][64 * 72];
  __shared__ __hip_bfloat16 Bhi[2][192 * 64];
  __shared__ __hip_bfloat16 Blo[2][128 * 64];

  const int tid  = threadIdx.x;
  const int wave = tid >> 6;
  const int lane = tid & 63;
  const int row0 = blockIdx.x * 64;

  const int lr = tid >> 2;
  const int le = (tid & 3) * 16;
  const float* xrow = x + (row0 + lr) * 1024 + le;

  f32x4 acc[12];
#pragma unroll
  for (int j = 0; j < 12; ++j) acc[j] = f32x4{0.f, 0.f, 0.f, 0.f};

  const int l15 = lane & 15, l4 = lane >> 4;

  auto issue_B = [&](int c, int buf) {
    const int g = (lane & 7) ^ ((lane >> 3) & 7);
#pragma unroll
    for (int s = 0; s < 6; ++s) {
      const int qq = wave * 6 + s;
      const int n  = qq * 8 + (lane >> 3);
      gload_lds16(Wthi + n * 1024 + c * 64 + g * 8, &Bhi[buf][qq * 512]);
      if (qq < 16)
        gload_lds16(Wtlo + n * 1024 + c * 64 + g * 8, &Blo[buf][qq * 512]);
    }
  };
  auto write_A = [&](int buf, const f32x4* xr) {
    short8 h0, h1, l0, l1;
    const float* xf = (const float*)xr;
#pragma unroll
    for (int j = 0; j < 8; ++j) {
      const float v = xf[j];
      const short h = f2bf(v);
      h0[j] = h;
      l0[j] = f2bf(v - bf2f(h));
    }
#pragma unroll
    for (int j = 0; j < 8; ++j) {
      const float v = xf[8 + j];
      const short h = f2bf(v);
      h1[j] = h;
      l1[j] = f2bf(v - bf2f(h));
    }
    *(short8*)&Ahi[buf][lr * 72 + le]     = h0;
    *(short8*)&Ahi[buf][lr * 72 + le + 8] = h1;
    *(short8*)&Alo[buf][lr * 72 + le]     = l0;
    *(short8*)&Alo[buf][lr * 72 + le + 8] = l1;
  };
  auto compute = [&](int buf) {
    const int tr = wave * 16 + l15;
    short8 ah0 = *(const short8*)&Ahi[buf][tr * 72 + l4 * 8];
    short8 ah1 = *(const short8*)&Ahi[buf][tr * 72 + 32 + l4 * 8];
    short8 al0 = *(const short8*)&Alo[buf][tr * 72 + l4 * 8];
    short8 al1 = *(const short8*)&Alo[buf][tr * 72 + 32 + l4 * 8];
#pragma unroll
    for (int j = 0; j < 12; ++j) {
      const int n  = j * 16 + l15;
      const int o0 = ((l4)     ^ (n & 7)) * 8;
      const int o1 = ((4 + l4) ^ (n & 7)) * 8;
      short8 bh0 = *(const short8*)&Bhi[buf][n * 64 + o0];
      short8 bh1 = *(const short8*)&Bhi[buf][n * 64 + o1];
      acc[j] = mfma_16x16x32(ah0, bh0, acc[j]);
      acc[j] = mfma_16x16x32(ah1, bh1, acc[j]);
      if (j < 8) {
        short8 bl0 = *(const short8*)&Blo[buf][n * 64 + o0];
        short8 bl1 = *(const short8*)&Blo[buf][n * 64 + o1];
        acc[j] = mfma_16x16x32(ah0, bl0, acc[j]);
        acc[j] = mfma_16x16x32(ah1, bl1, acc[j]);
        acc[j] = mfma_16x16x32(al0, bh0, acc[j]);
        acc[j] = mfma_16x16x32(al1, bh1, acc[j]);
      }
    }
  };

  f32x4 xr[4], xn[4];
  {
    const f32x4* p = (const f32x4*)xrow;
    xr[0] = p[0]; xr[1] = p[1]; xr[2] = p[2]; xr[3] = p[3];
  }
  issue_B(0, 0);
  __builtin_amdgcn_s_waitcnt(0);
  write_A(0, xr);
  __syncthreads();

  for (int c = 0; c < 16; ++c) {
    const int p = c & 1;
    if (c < 15) {
      const f32x4* pp = (const f32x4*)(xrow + (c + 1) * 64);
      xn[0] = pp[0]; xn[1] = pp[1]; xn[2] = pp[2]; xn[3] = pp[3];
      issue_B(c + 1, p ^ 1);
    }
    compute(p);
    if (c < 15) {
      __builtin_amdgcn_s_waitcnt(0);
      write_A(p ^ 1, xn);
    }
    __syncthreads();
  }

  const int strip = wave * 16;
#pragma unroll
  for (int j = 0; j < 12; ++j) {
    const int n  = j * 16 + l15;
    const int mm = n >> 6;
    const int h  = n & 63;
#pragma unroll
    for (int r = 0; r < 4; ++r) {
      const int trow = row0 + strip + l4 * 4 + r;
      const float val = acc[j][r];
      const __hip_bfloat16 hi = __float2bfloat16(val);
      const __hip_bfloat16 lo = __float2bfloat16(val - __bfloat162float(hi));
      if (mm == 0) {
        qhi[trow * 64 + h] = hi;
        qlo[trow * 64 + h] = lo;
      } else if (mm == 1) {
        khi[trow * 64 + h] = hi;
        klo[trow * 64 + h] = lo;
      } else {
        const int bb = trow >> 11, tl = trow & 2047;
        vT[(bb * 64 + h) * 2048 + tl] = hi;
      }
    }
  }
}

// ---------------------------------------------------------------------------
// Kernel B v5: XCD-local balanced split-K flash attention.
// Grid 640 = 8 batches x 80 units; b = bid&7 keeps each batch's K/V/Q on one
// XCD's L2 (the R4 property that gave FETCH=5MB). Strip s (s+1 causal K-tiles
// of 64 keys over 64 Q-rows) gets ceil((s+1)/8) units -> <=8 tiles/unit; the
// block's 4 waves take tiles stride-4 -> <=2 tiles/wave (balanced). In-block
// cross-wave merge reuses Psm (bf16) -> LDS 39KB, VGPR 128 -> 4 blocks/CU
// capacity. One normalized bf16 partial per unit; attn_merge combines <=4.
// ---------------------------------------------------------------------------
__global__ __launch_bounds__(256, 2) void attn_part(
    const __hip_bfloat16* __restrict__ qhi, const __hip_bfloat16* __restrict__ qlo,
    const __hip_bfloat16* __restrict__ khi, const __hip_bfloat16* __restrict__ klo,
    const __hip_bfloat16* __restrict__ vT,
    __hip_bfloat16* __restrict__ partO, float* __restrict__ partM,
    float* __restrict__ partL) {
  __shared__ __hip_bfloat16 Psm[4][64 * 72];   // P round-trip; reused for merge
  __shared__ float Msm[4][64];
  __shared__ float Lsm[4][64];

  const int tid  = threadIdx.x;
  const int wave = tid >> 6;
  const int lane = tid & 63;
  const int l15 = lane & 15, l4 = lane >> 4;

  // ---- decode unit: b on XCD bid&7; u ordered big-strip-first ----
  const int b = blockIdx.x & 7;
  const int u = blockIdx.x >> 3;     // 0..79
  int s, ci;
  if (u < 32)      { s = 31 - (u >> 2);          ci = u & 3; }          // ns=4
  else if (u < 56) { s = 23 - (u - 32) / 3;      ci = (u - 32) % 3; }   // ns=3
  else if (u < 72) { s = 15 - ((u - 56) >> 1);   ci = (u - 56) & 1; }   // ns=2
  else             { s = 7  - (u - 72);          ci = 0; }              // ns=1
  const int ntile = s + 1;
  const int ns    = (s < 8) ? 1 : (s < 16) ? 2 : (s < 24) ? 3 : 4;
  const int base  = ntile / ns, rem = ntile % ns;
  const int tb    = ci * base + ((ci < rem) ? ci : rem);
  const int tcnt  = base + ((ci < rem) ? 1 : 0);
  const int t0    = s * 64;
  const int pidx  = (b * 32 + s) * 4 + ci;

  // ---- Q A-frags for 4 sub-tiles, hi+lo, in regs throughout ----
  short8 qh0[4], qh1[4], ql0[4], ql1[4];
#pragma unroll
  for (int m = 0; m < 4; ++m) {
    const __hip_bfloat16* qph = qhi + (b * 2048 + t0 + m * 16 + l15) * 64;
    const __hip_bfloat16* qpl = qlo + (b * 2048 + t0 + m * 16 + l15) * 64;
    qh0[m] = *(const short8*)(qph + l4 * 8);
    qh1[m] = *(const short8*)(qph + 32 + l4 * 8);
    ql0[m] = *(const short8*)(qpl + l4 * 8);
    ql1[m] = *(const short8*)(qpl + 32 + l4 * 8);
  }

  f32x4 acc[4][4];
#pragma unroll
  for (int m = 0; m < 4; ++m)
#pragma unroll
    for (int j = 0; j < 4; ++j) acc[m][j] = f32x4{0.f, 0.f, 0.f, 0.f};
  float m_[4][4], l_[4][4];
#pragma unroll
  for (int m = 0; m < 4; ++m)
#pragma unroll
    for (int r = 0; r < 4; ++r) { m_[m][r] = -1e30f; l_[m][r] = 0.f; }

  const __hip_bfloat16* kbase_h = khi + (size_t)b * 2048 * 64;
  const __hip_bfloat16* kbase_l = klo + (size_t)b * 2048 * 64;
  const __hip_bfloat16* vbase   = vT + (size_t)b * 64 * 2048;

  // ---- K-loop: this wave takes tiles tb+wave, tb+wave+4, ... (<=2) ----
  for (int kt = tb + wave; kt < tb + tcnt; kt += 4) {
    const int k0 = kt << 6;
    const bool diag = (kt == s);

    short8 kh0[4], kh1[4], kl0[4], kl1[4];
#pragma unroll
    for (int j = 0; j < 4; ++j) {
      const __hip_bfloat16* kph = kbase_h + (k0 + j * 16 + l15) * 64;
      const __hip_bfloat16* kpl = kbase_l + (k0 + j * 16 + l15) * 64;
      kh0[j] = *(const short8*)(kph + l4 * 8);
      kh1[j] = *(const short8*)(kph + 32 + l4 * 8);
      kl0[j] = *(const short8*)(kpl + l4 * 8);
      kl1[j] = *(const short8*)(kpl + 32 + l4 * 8);
    }

#pragma unroll
    for (int m = 0; m < 4; ++m) {
      f32x4 s_[4];
#pragma unroll
      for (int j = 0; j < 4; ++j) {
        if (diag && j > m) {
          s_[j] = f32x4{-1e30f, -1e30f, -1e30f, -1e30f};
          continue;
        }
        f32x4 z = f32x4{0.f, 0.f, 0.f, 0.f};
        z = mfma_16x16x32(qh0[m], kh0[j], z);
        z = mfma_16x16x32(qh1[m], kh1[j], z);
        z = mfma_16x16x32(qh0[m], kl0[j], z);
        z = mfma_16x16x32(qh1[m], kl1[j], z);
        z = mfma_16x16x32(ql0[m], kh0[j], z);
        z = mfma_16x16x32(ql1[m], kh1[j], z);
        s_[j] = z;
      }
      if (diag) {   // partial mask on the j == m sub-block
        const int key = m * 16 + l15;
#pragma unroll
        for (int r = 0; r < 4; ++r) {
          const int row = m * 16 + l4 * 4 + r;
          if (key > row) s_[m][r] = -1e30f;
        }
      }

      float mx[4], rs[4], al[4];
#pragma unroll
      for (int r = 0; r < 4; ++r)
        mx[r] = fmaxf(fmaxf(s_[0][r], s_[1][r]), fmaxf(s_[2][r], s_[3][r]));
      for (int off = 1; off < 16; off <<= 1) {
#pragma unroll
        for (int r = 0; r < 4; ++r) mx[r] = fmaxf(mx[r], __shfl_xor(mx[r], off));
      }
#pragma unroll
      for (int r = 0; r < 4; ++r) {
        const float mn = fmaxf(m_[m][r], mx[r]);
        al[r] = __expf(m_[m][r] - mn);
        m_[m][r] = mn;
        rs[r] = 0.f;
      }
#pragma unroll
      for (int j = 0; j < 4; ++j) {
#pragma unroll
        for (int r = 0; r < 4; ++r) {
          const float pv = __expf(s_[j][r] - m_[m][r]);
          s_[j][r] = pv;
          rs[r] += pv;
        }
      }
      for (int off = 1; off < 16; off <<= 1) {
#pragma unroll
        for (int r = 0; r < 4; ++r) rs[r] += __shfl_xor(rs[r], off);
      }
#pragma unroll
      for (int r = 0; r < 4; ++r) l_[m][r] = l_[m][r] * al[r] + rs[r];
#pragma unroll
      for (int j = 0; j < 4; ++j)
#pragma unroll
        for (int r = 0; r < 4; ++r) acc[m][j][r] *= al[r];

#pragma unroll
      for (int j = 0; j < 4; ++j)
#pragma unroll
        for (int r = 0; r < 4; ++r)
          Psm[wave][(m * 16 + l4 * 4 + r) * 72 + j * 16 + l15] =
              __float2bfloat16(s_[j][r]);
    }

    // ---- V frags (stay in flight across the lgkm-only wait) ----
    short8 vf0[4], vf1[4];
#pragma unroll
    for (int j = 0; j < 4; ++j) {
      const __hip_bfloat16* vp = vbase + (j * 16 + l15) * 2048 + k0;
      vf0[j] = *(const short8*)(vp + l4 * 8);
      vf1[j] = *(const short8*)(vp + 32 + l4 * 8);
    }

    WAIT_LGKM0();   // P LDS write->read only; vmcnt untouched

#pragma unroll
    for (int m = 0; m < 4; ++m) {
      short8 pf0 = *(const short8*)&Psm[wave][(m * 16 + l15) * 72 + l4 * 8];
      short8 pf1 = *(const short8*)&Psm[wave][(m * 16 + l15) * 72 + 32 + l4 * 8];
#pragma unroll
      for (int j = 0; j < 4; ++j) {
        acc[m][j] = mfma_16x16x32(pf0, vf0[j], acc[m][j]);
        acc[m][j] = mfma_16x16x32(pf1, vf1[j], acc[m][j]);
      }
    }
  }

  // ---- per-wave partials into LDS (Psm reused as bf16 acc buffer) ----
#pragma unroll
  for (int m = 0; m < 4; ++m)
#pragma unroll
    for (int j = 0; j < 4; ++j)
#pragma unroll
      for (int r = 0; r < 4; ++r)
        Psm[wave][(m * 16 + l4 * 4 + r) * 72 + j * 16 + l15] =
            __float2bfloat16(acc[m][j][r]);
  if (l15 == 0) {
#pragma unroll
    for (int m = 0; m < 4; ++m)
#pragma unroll
      for (int r = 0; r < 4; ++r) {
        Msm[wave][m * 16 + l4 * 4 + r] = m_[m][r];
        Lsm[wave][m * 16 + l4 * 4 + r] = l_[m][r];
      }
  }
  __syncthreads();

  // ---- cross-wave merge: wave handles rows [wave*16,+16), lane = h ----
  const size_t pbase = (size_t)pidx * 4096;
#pragma unroll
  for (int rr = 0; rr < 16; ++rr) {
    const int row = wave * 16 + rr;
    float M = fmaxf(fmaxf(Msm[0][row], Msm[1][row]),
                    fmaxf(Msm[2][row], Msm[3][row]));
    float L = 0.f, O = 0.f;
#pragma unroll
    for (int w2 = 0; w2 < 4; ++w2) {
      const float a = __expf(Msm[w2][row] - M);
      L += a * Lsm[w2][row];
      O += a * __bfloat162float(Psm[w2][row * 72 + lane]);
    }
    partO[pbase + row * 64 + lane] = __float2bfloat16((L > 0.f) ? O / L : 0.f);
    if (lane == 0) {
      partM[pidx * 64 + row] = M;
      partL[pidx * 64 + row] = L;
    }
  }
}

// ---------------------------------------------------------------------------
// Kernel C: merge <=4 partials per (b, strip). Grid 256 x 256 threads.
// ---------------------------------------------------------------------------
__global__ __launch_bounds__(256) void attn_merge(
    const __hip_bfloat16* __restrict__ partO, const float* __restrict__ partM,
    const float* __restrict__ partL, float* __restrict__ out) {
  const int bs = blockIdx.x;          // b*32 + s
  const int b = bs >> 5, s = bs & 31;
  const int ns = (s < 8) ? 1 : (s < 16) ? 2 : (s < 24) ? 3 : 4;
  const int tid = threadIdx.x;
  const int h = tid & 63, rg = tid >> 6;
  const int pb = bs * 4;

  for (int rr = 0; rr < 16; ++rr) {
    const int row = rg * 16 + rr;
    float M = -1e30f;
    for (int c = 0; c < ns; ++c) M = fmaxf(M, partM[(pb + c) * 64 + row]);
    float L = 0.f, O = 0.f;
    for (int c = 0; c < ns; ++c) {
      const float a = __expf(partM[(pb + c) * 64 + row] - M) *
                      partL[(pb + c) * 64 + row];
      L += a;
      O += a * __bfloat162float(partO[(size_t)(pb + c) * 4096 + row * 64 + h]);
    }
    out[(b * 2048 + s * 64 + row) * 64 + h] = O / L;
  }
}

// ---------------------------------------------------------------------------
extern "C" void kernel_launch(void* const* d_in, const int* in_sizes, int n_in,
                              void* d_out, int out_size, void* d_ws, size_t ws_size,
                              hipStream_t stream) {
  const float* x  = (const float*)d_in[0];
  const float* Wq = (const float*)d_in[1];
  const float* Wk = (const float*)d_in[2];
  const float* Wv = (const float*)d_in[3];
  float* out = (float*)d_out;

  char* ws = (char*)d_ws;
  __hip_bfloat16* Wthi = (__hip_bfloat16*)ws;                   // 384 KB
  __hip_bfloat16* Wtlo = (__hip_bfloat16*)(ws + 393216);        // 384 KB
  __hip_bfloat16* qhi  = (__hip_bfloat16*)(ws + 786432);        // 2 MB each
  __hip_bfloat16* qlo  = (__hip_bfloat16*)(ws + 786432 + 1 * 2097152);
  __hip_bfloat16* khi  = (__hip_bfloat16*)(ws + 786432 + 2 * 2097152);
  __hip_bfloat16* klo  = (__hip_bfloat16*)(ws + 786432 + 3 * 2097152);
  __hip_bfloat16* vT   = (__hip_bfloat16*)(ws + 786432 + 4 * 2097152);
  char* p = ws + 786432 + 5 * 2097152;                          // 11.27 MB
  __hip_bfloat16* partO = (__hip_bfloat16*)p;                   // 8.39 MB
  float* partM = (float*)(p + 8388608);                         // 256 KB
  float* partL = (float*)(p + 8388608 + 262144);                // 256 KB

  prep_w<<<192, 256, 0, stream>>>(Wq, Wk, Wv, Wthi, Wtlo);
  qkv_gemm<<<256, 256, 0, stream>>>(x, Wthi, Wtlo, qhi, qlo, khi, klo, vT);
  attn_part<<<640, 256, 0, stream>>>(qhi, qlo, khi, klo, vT, partO, partM, partL);
  attn_merge<<<256, 256, 0, stream>>>(partO, partM, partL, out);
}

// Round 7
// 159.626 us; speedup vs baseline: 1.5824x; 1.5184x over previous
//
#include <hip/hip_runtime.h>
#include <hip/hip_bf16.h>

// Problem constants
#define BB 8
#define TT 2048
#define EE 1024
#define HH 64

typedef __attribute__((ext_vector_type(8))) short short8;
typedef __attribute__((ext_vector_type(4))) float f32x4;

__device__ inline f32x4 mfma_16x16x32(short8 a, short8 b, f32x4 c) {
  return __builtin_amdgcn_mfma_f32_16x16x32_bf16(a, b, c, 0, 0, 0);
}

// async global->LDS, 16B per lane, LDS dest = wave-uniform base + lane*16
__device__ inline void gload_lds16(const __hip_bfloat16* g, __hip_bfloat16* l) {
  __builtin_amdgcn_global_load_lds((const __attribute__((address_space(1))) void*)g,
                                   (__attribute__((address_space(3))) void*)l,
                                   16, 0, 0);
}

__device__ inline short f2bf(float f) {
  __hip_bfloat16 h = __float2bfloat16(f);
  return *reinterpret_cast<short*>(&h);
}
__device__ inline float bf2f(short s) {
  __hip_bfloat16 h = *reinterpret_cast<__hip_bfloat16*>(&s);
  return __bfloat162float(h);
}

// wait lgkmcnt(0) only; leave vmcnt/expcnt unconstrained
#define WAIT_LGKM0() __builtin_amdgcn_s_waitcnt(0xC07F)

// ---------------------------------------------------------------------------
// Kernel 0: split-precision transposed weights (unchanged).
// ---------------------------------------------------------------------------
__global__ void prep_w(const float* __restrict__ Wq, const float* __restrict__ Wk,
                       const float* __restrict__ Wv,
                       __hip_bfloat16* __restrict__ Wthi,
                       __hip_bfloat16* __restrict__ Wtlo) {
  const int n = blockIdx.x;          // 0..191
  const int m = n >> 6;
  const int h = n & 63;
  const float* W = (m == 0) ? Wq : (m == 1) ? Wk : Wv;
  const int e0 = threadIdx.x * 4;    // 256 threads * 4 = 1024
#pragma unroll
  for (int j = 0; j < 4; ++j) {
    const float w = W[(e0 + j) * 64 + h];
    const __hip_bfloat16 hi = __float2bfloat16(w);
    Wthi[n * 1024 + e0 + j] = hi;
    Wtlo[n * 1024 + e0 + j] = __float2bfloat16(w - __bfloat162float(hi));
  }
}

// ---------------------------------------------------------------------------
// Kernel A (unchanged this round): split-bf16 fp32-emulated GEMM.
// ---------------------------------------------------------------------------
__global__ __launch_bounds__(256) void qkv_gemm(
    const float* __restrict__ x,
    const __hip_bfloat16* __restrict__ Wthi, const __hip_bfloat16* __restrict__ Wtlo,
    __hip_bfloat16* __restrict__ qhi, __hip_bfloat16* __restrict__ qlo,
    __hip_bfloat16* __restrict__ khi, __hip_bfloat16* __restrict__ klo,
    __hip_bfloat16* __restrict__ vT) {
  __shared__ __hip_bfloat16 Ahi[2][64 * 72];
  __shared__ __hip_bfloat16 Alo[2][64 * 72];
  __shared__ __hip_bfloat16 Bhi[2][192 * 64];
  __shared__ __hip_bfloat16 Blo[2][128 * 64];

  const int tid  = threadIdx.x;
  const int wave = tid >> 6;
  const int lane = tid & 63;
  const int row0 = blockIdx.x * 64;

  const int lr = tid >> 2;
  const int le = (tid & 3) * 16;
  const float* xrow = x + (row0 + lr) * 1024 + le;

  f32x4 acc[12];
#pragma unroll
  for (int j = 0; j < 12; ++j) acc[j] = f32x4{0.f, 0.f, 0.f, 0.f};

  const int l15 = lane & 15, l4 = lane >> 4;

  auto issue_B = [&](int c, int buf) {
    const int g = (lane & 7) ^ ((lane >> 3) & 7);
#pragma unroll
    for (int s = 0; s < 6; ++s) {
      const int qq = wave * 6 + s;
      const int n  = qq * 8 + (lane >> 3);
      gload_lds16(Wthi + n * 1024 + c * 64 + g * 8, &Bhi[buf][qq * 512]);
      if (qq < 16)
        gload_lds16(Wtlo + n * 1024 + c * 64 + g * 8, &Blo[buf][qq * 512]);
    }
  };
  auto write_A = [&](int buf, const f32x4* xr) {
    short8 h0, h1, l0, l1;
    const float* xf = (const float*)xr;
#pragma unroll
    for (int j = 0; j < 8; ++j) {
      const float v = xf[j];
      const short h = f2bf(v);
      h0[j] = h;
      l0[j] = f2bf(v - bf2f(h));
    }
#pragma unroll
    for (int j = 0; j < 8; ++j) {
      const float v = xf[8 + j];
      const short h = f2bf(v);
      h1[j] = h;
      l1[j] = f2bf(v - bf2f(h));
    }
    *(short8*)&Ahi[buf][lr * 72 + le]     = h0;
    *(short8*)&Ahi[buf][lr * 72 + le + 8] = h1;
    *(short8*)&Alo[buf][lr * 72 + le]     = l0;
    *(short8*)&Alo[buf][lr * 72 + le + 8] = l1;
  };
  auto compute = [&](int buf) {
    const int tr = wave * 16 + l15;
    short8 ah0 = *(const short8*)&Ahi[buf][tr * 72 + l4 * 8];
    short8 ah1 = *(const short8*)&Ahi[buf][tr * 72 + 32 + l4 * 8];
    short8 al0 = *(const short8*)&Alo[buf][tr * 72 + l4 * 8];
    short8 al1 = *(const short8*)&Alo[buf][tr * 72 + 32 + l4 * 8];
#pragma unroll
    for (int j = 0; j < 12; ++j) {
      const int n  = j * 16 + l15;
      const int o0 = ((l4)     ^ (n & 7)) * 8;
      const int o1 = ((4 + l4) ^ (n & 7)) * 8;
      short8 bh0 = *(const short8*)&Bhi[buf][n * 64 + o0];
      short8 bh1 = *(const short8*)&Bhi[buf][n * 64 + o1];
      acc[j] = mfma_16x16x32(ah0, bh0, acc[j]);
      acc[j] = mfma_16x16x32(ah1, bh1, acc[j]);
      if (j < 8) {
        short8 bl0 = *(const short8*)&Blo[buf][n * 64 + o0];
        short8 bl1 = *(const short8*)&Blo[buf][n * 64 + o1];
        acc[j] = mfma_16x16x32(ah0, bl0, acc[j]);
        acc[j] = mfma_16x16x32(ah1, bl1, acc[j]);
        acc[j] = mfma_16x16x32(al0, bh0, acc[j]);
        acc[j] = mfma_16x16x32(al1, bh1, acc[j]);
      }
    }
  };

  f32x4 xr[4], xn[4];
  {
    const f32x4* p = (const f32x4*)xrow;
    xr[0] = p[0]; xr[1] = p[1]; xr[2] = p[2]; xr[3] = p[3];
  }
  issue_B(0, 0);
  __builtin_amdgcn_s_waitcnt(0);
  write_A(0, xr);
  __syncthreads();

  for (int c = 0; c < 16; ++c) {
    const int p = c & 1;
    if (c < 15) {
      const f32x4* pp = (const f32x4*)(xrow + (c + 1) * 64);
      xn[0] = pp[0]; xn[1] = pp[1]; xn[2] = pp[2]; xn[3] = pp[3];
      issue_B(c + 1, p ^ 1);
    }
    compute(p);
    if (c < 15) {
      __builtin_amdgcn_s_waitcnt(0);
      write_A(p ^ 1, xn);
    }
    __syncthreads();
  }

  const int strip = wave * 16;
#pragma unroll
  for (int j = 0; j < 12; ++j) {
    const int n  = j * 16 + l15;
    const int mm = n >> 6;
    const int h  = n & 63;
#pragma unroll
    for (int r = 0; r < 4; ++r) {
      const int trow = row0 + strip + l4 * 4 + r;
      const float val = acc[j][r];
      const __hip_bfloat16 hi = __float2bfloat16(val);
      const __hip_bfloat16 lo = __float2bfloat16(val - __bfloat162float(hi));
      if (mm == 0) {
        qhi[trow * 64 + h] = hi;
        qlo[trow * 64 + h] = lo;
      } else if (mm == 1) {
        khi[trow * 64 + h] = hi;
        klo[trow * 64 + h] = lo;
      } else {
        const int bb = trow >> 11, tl = trow & 2047;
        vT[(bb * 64 + h) * 2048 + tl] = hi;
      }
    }
  }
}

// ---------------------------------------------------------------------------
// Kernel B v6: no-spill split-K flash attention, single kernel, direct out.
// 32 Q-rows per wave (2 MFMA sub-tiles: Q 32 + acc 32 VGPRs). Block = 4 waves
// owning the SAME 32-row strip; the strip's ss/2+1 causal K-tiles are split
// stride-4 across waves; fp32 in-block merge via LDS; direct out write.
// Grid 512 = 8 batches (bid&7, XCD-local) x 64 strips (big-first). K/V frags
// load straight global->VGPR (each tile consumed by exactly one wave).
// launch_bounds(256,2) -> 256 VGPR cap: NO SPILLS (R4-R6's hidden killer).
// ---------------------------------------------------------------------------
__global__ __launch_bounds__(256, 2) void attn(
    const __hip_bfloat16* __restrict__ qhi, const __hip_bfloat16* __restrict__ qlo,
    const __hip_bfloat16* __restrict__ khi, const __hip_bfloat16* __restrict__ klo,
    const __hip_bfloat16* __restrict__ vT, float* __restrict__ out) {
  __shared__ __hip_bfloat16 Psm[4][2][16 * 72];  // per-wave, per-m P transpose
  __shared__ float Osm[4][32][65];               // per-wave partial O (fp32)
  __shared__ float Msm[4][32];
  __shared__ float Lsm[4][32];

  const int tid  = threadIdx.x;
  const int wave = tid >> 6;
  const int lane = tid & 63;
  const int l15 = lane & 15, l4 = lane >> 4;

  const int b  = blockIdx.x & 7;            // XCD-local batch
  const int ss = 63 - (blockIdx.x >> 3);    // 32-row strip, big-work first
  const int t0 = ss * 32;
  const int ntiles = (ss >> 1) + 1;         // causal 64-key tiles

  // ---- Q A-frags for 2 sub-tiles, hi+lo (32 VGPRs) ----
  short8 qh0[2], qh1[2], ql0[2], ql1[2];
#pragma unroll
  for (int m = 0; m < 2; ++m) {
    const __hip_bfloat16* qph = qhi + (b * 2048 + t0 + m * 16 + l15) * 64;
    const __hip_bfloat16* qpl = qlo + (b * 2048 + t0 + m * 16 + l15) * 64;
    qh0[m] = *(const short8*)(qph + l4 * 8);
    qh1[m] = *(const short8*)(qph + 32 + l4 * 8);
    ql0[m] = *(const short8*)(qpl + l4 * 8);
    ql1[m] = *(const short8*)(qpl + 32 + l4 * 8);
  }

  f32x4 acc[2][4];
#pragma unroll
  for (int m = 0; m < 2; ++m)
#pragma unroll
    for (int j = 0; j < 4; ++j) acc[m][j] = f32x4{0.f, 0.f, 0.f, 0.f};
  float m_[2][4], l_[2][4];
#pragma unroll
  for (int m = 0; m < 2; ++m)
#pragma unroll
    for (int r = 0; r < 4; ++r) { m_[m][r] = -1e30f; l_[m][r] = 0.f; }

  const __hip_bfloat16* kbase_h = khi + (size_t)b * 2048 * 64;
  const __hip_bfloat16* kbase_l = klo + (size_t)b * 2048 * 64;
  const __hip_bfloat16* vbase   = vT + (size_t)b * 64 * 2048;

  // ---- K-loop: wave takes tiles wave, wave+4, ... ----
  for (int kt = wave; kt < ntiles; kt += 4) {
    const int k0 = kt << 6;
    const bool diag = (kt == ntiles - 1);

    // K frags for all 4 j-groups (64 VGPRs transient, shared across m)
    short8 kh0[4], kh1[4], kl0[4], kl1[4];
#pragma unroll
    for (int j = 0; j < 4; ++j) {
      const __hip_bfloat16* kph = kbase_h + (k0 + j * 16 + l15) * 64;
      const __hip_bfloat16* kpl = kbase_l + (k0 + j * 16 + l15) * 64;
      kh0[j] = *(const short8*)(kph + l4 * 8);
      kh1[j] = *(const short8*)(kph + 32 + l4 * 8);
      kl0[j] = *(const short8*)(kpl + l4 * 8);
      kl1[j] = *(const short8*)(kpl + 32 + l4 * 8);
    }

#pragma unroll
    for (int m = 0; m < 2; ++m) {
      const int rowbase = t0 + m * 16;     // rows rowbase..rowbase+15
      f32x4 s_[4];
#pragma unroll
      for (int j = 0; j < 4; ++j) {
        if (diag && (k0 + j * 16) > (rowbase + 15)) {  // fully masked group
          s_[j] = f32x4{-1e30f, -1e30f, -1e30f, -1e30f};
          continue;
        }
        f32x4 z = f32x4{0.f, 0.f, 0.f, 0.f};
        z = mfma_16x16x32(qh0[m], kh0[j], z);
        z = mfma_16x16x32(qh1[m], kh1[j], z);
        z = mfma_16x16x32(qh0[m], kl0[j], z);
        z = mfma_16x16x32(qh1[m], kl1[j], z);
        z = mfma_16x16x32(ql0[m], kh0[j], z);
        z = mfma_16x16x32(ql1[m], kh1[j], z);
        s_[j] = z;
      }
      if (diag) {   // partial mask where key > row
#pragma unroll
        for (int j = 0; j < 4; ++j) {
          const int key = k0 + j * 16 + l15;
#pragma unroll
          for (int r = 0; r < 4; ++r) {
            const int row = rowbase + l4 * 4 + r;
            if (key > row) s_[j][r] = -1e30f;
          }
        }
      }

      // online softmax (4 rows/lane; reduce across 16-lane col groups)
      float mx[4], rs[4], al[4];
#pragma unroll
      for (int r = 0; r < 4; ++r)
        mx[r] = fmaxf(fmaxf(s_[0][r], s_[1][r]), fmaxf(s_[2][r], s_[3][r]));
      for (int off = 1; off < 16; off <<= 1) {
#pragma unroll
        for (int r = 0; r < 4; ++r) mx[r] = fmaxf(mx[r], __shfl_xor(mx[r], off));
      }
#pragma unroll
      for (int r = 0; r < 4; ++r) {
        const float mn = fmaxf(m_[m][r], mx[r]);
        al[r] = __expf(m_[m][r] - mn);
        m_[m][r] = mn;
        rs[r] = 0.f;
      }
#pragma unroll
      for (int j = 0; j < 4; ++j) {
#pragma unroll
        for (int r = 0; r < 4; ++r) {
          const float pv = __expf(s_[j][r] - m_[m][r]);
          s_[j][r] = pv;
          rs[r] += pv;
        }
      }
      for (int off = 1; off < 16; off <<= 1) {
#pragma unroll
        for (int r = 0; r < 4; ++r) rs[r] += __shfl_xor(rs[r], off);
      }
#pragma unroll
      for (int r = 0; r < 4; ++r) l_[m][r] = l_[m][r] * al[r] + rs[r];
#pragma unroll
      for (int j = 0; j < 4; ++j)
#pragma unroll
        for (int r = 0; r < 4; ++r) acc[m][j][r] *= al[r];

      // P (C-layout) -> per-wave per-m LDS buffer
#pragma unroll
      for (int j = 0; j < 4; ++j)
#pragma unroll
        for (int r = 0; r < 4; ++r)
          Psm[wave][m][(l4 * 4 + r) * 72 + j * 16 + l15] =
              __float2bfloat16(s_[j][r]);
    }

    // ---- V frags (stay in flight across the lgkm-only wait) ----
    short8 vf0[4], vf1[4];
#pragma unroll
    for (int j = 0; j < 4; ++j) {
      const __hip_bfloat16* vp = vbase + (j * 16 + l15) * 2048 + k0;
      vf0[j] = *(const short8*)(vp + l4 * 8);
      vf1[j] = *(const short8*)(vp + 32 + l4 * 8);
    }

    WAIT_LGKM0();   // P LDS writes visible to same wave; vmcnt untouched

    // ---- O += P V ----
#pragma unroll
    for (int m = 0; m < 2; ++m) {
      short8 pf0 = *(const short8*)&Psm[wave][m][l15 * 72 + l4 * 8];
      short8 pf1 = *(const short8*)&Psm[wave][m][l15 * 72 + 32 + l4 * 8];
#pragma unroll
      for (int j = 0; j < 4; ++j) {
        acc[m][j] = mfma_16x16x32(pf0, vf0[j], acc[m][j]);
        acc[m][j] = mfma_16x16x32(pf1, vf1[j], acc[m][j]);
      }
    }
  }

  // ---- per-wave partials into LDS (fp32) ----
#pragma unroll
  for (int m = 0; m < 2; ++m) {
#pragma unroll
    for (int j = 0; j < 4; ++j)
#pragma unroll
      for (int r = 0; r < 4; ++r)
        Osm[wave][m * 16 + l4 * 4 + r][j * 16 + l15] = acc[m][j][r];
    if (l15 == 0) {
#pragma unroll
      for (int r = 0; r < 4; ++r) {
        Msm[wave][m * 16 + l4 * 4 + r] = m_[m][r];
        Lsm[wave][m * 16 + l4 * 4 + r] = l_[m][r];
      }
    }
  }
  __syncthreads();

  // ---- cross-wave merge: wave handles rows [wave*8, +8), lane = h ----
#pragma unroll
  for (int rr = 0; rr < 8; ++rr) {
    const int row = wave * 8 + rr;
    float M = fmaxf(fmaxf(Msm[0][row], Msm[1][row]),
                    fmaxf(Msm[2][row], Msm[3][row]));
    float L = 0.f, O = 0.f;
#pragma unroll
    for (int w2 = 0; w2 < 4; ++w2) {
      const float a = __expf(Msm[w2][row] - M);
      L += a * Lsm[w2][row];
      O += a * Osm[w2][row][lane];
    }
    out[(b * 2048 + t0 + row) * 64 + lane] = O / L;
  }
}

// ---------------------------------------------------------------------------
extern "C" void kernel_launch(void* const* d_in, const int* in_sizes, int n_in,
                              void* d_out, int out_size, void* d_ws, size_t ws_size,
                              hipStream_t stream) {
  const float* x  = (const float*)d_in[0];
  const float* Wq = (const float*)d_in[1];
  const float* Wk = (const float*)d_in[2];
  const float* Wv = (const float*)d_in[3];
  float* out = (float*)d_out;

  char* ws = (char*)d_ws;
  __hip_bfloat16* Wthi = (__hip_bfloat16*)ws;                   // 384 KB
  __hip_bfloat16* Wtlo = (__hip_bfloat16*)(ws + 393216);        // 384 KB
  __hip_bfloat16* qhi  = (__hip_bfloat16*)(ws + 786432);        // 2 MB each
  __hip_bfloat16* qlo  = (__hip_bfloat16*)(ws + 786432 + 1 * 2097152);
  __hip_bfloat16* khi  = (__hip_bfloat16*)(ws + 786432 + 2 * 2097152);
  __hip_bfloat16* klo  = (__hip_bfloat16*)(ws + 786432 + 3 * 2097152);
  __hip_bfloat16* vT   = (__hip_bfloat16*)(ws + 786432 + 4 * 2097152);

  prep_w<<<192, 256, 0, stream>>>(Wq, Wk, Wv, Wthi, Wtlo);
  qkv_gemm<<<256, 256, 0, stream>>>(x, Wthi, Wtlo, qhi, qlo, khi, klo, vT);
  attn<<<512, 256, 0, stream>>>(qhi, qlo, khi, klo, vT, out);
}